// Round 1
// baseline (258.915 us; speedup 1.0000x reference)
//
#include <hip/hip_runtime.h>

// Problem constants (B=1, C=128, H=W=64)
#define NPOS 4096
#define NCH  128
#define NTOT (NPOS * NCH)   // 524288
#define NHEAD 4
#define DH    32

typedef __attribute__((ext_vector_type(8))) short short8;   // 8 bf16 (4 VGPRs)
typedef __attribute__((ext_vector_type(4))) float floatx4;  // MFMA acc

__device__ __forceinline__ unsigned short f2bf(float f) {
  unsigned int u = __float_as_uint(f);
  u += 0x7fffu + ((u >> 16) & 1u);   // RNE
  return (unsigned short)(u >> 16);
}

// ---------------- GroupNorm (num_groups=1) ----------------
// Pass 1: sum / sumsq over all 524288 elements. 65536 threads x 8 elems.
__global__ __launch_bounds__(256) void gn_reduce_k(const float* __restrict__ x,
                                                   float* __restrict__ stats) {
  int i = blockIdx.x * 256 + threadIdx.x;           // 0..65535
  float4 a = ((const float4*)x)[i];
  float4 b = ((const float4*)x)[i + 65536];
  float s  = a.x + a.y + a.z + a.w + b.x + b.y + b.z + b.w;
  float sq = a.x*a.x + a.y*a.y + a.z*a.z + a.w*a.w
           + b.x*b.x + b.y*b.y + b.z*b.z + b.w*b.w;
#pragma unroll
  for (int m = 1; m < 64; m <<= 1) {
    s  += __shfl_xor(s, m);
    sq += __shfl_xor(sq, m);
  }
  if ((threadIdx.x & 63) == 0) {
    atomicAdd(&stats[0], s);
    atomicAdd(&stats[1], sq);
  }
}

// Pass 2: h[c][n] = (x - mean)*rstd*w[c] + b[c], f32, float4 per thread.
__global__ __launch_bounds__(256) void gn_norm_k(const float* __restrict__ x,
                                                 const float* __restrict__ gw,
                                                 const float* __restrict__ gb,
                                                 const float* __restrict__ stats,
                                                 float* __restrict__ h) {
  int i = blockIdx.x * 256 + threadIdx.x;           // float4 index, 0..131071
  float mean = stats[0] * (1.0f / NTOT);
  float var  = stats[1] * (1.0f / NTOT) - mean * mean;
  float rstd = rsqrtf(var + 1e-5f);
  int c = i >> 10;                                  // 1024 float4 per channel
  float sw = gw[c] * rstd;
  float sb = gb[c] - mean * sw;
  float4 v = ((const float4*)x)[i];
  v.x = v.x * sw + sb; v.y = v.y * sw + sb;
  v.z = v.z * sw + sb; v.w = v.w * sw + sb;
  ((float4*)h)[i] = v;
}

// ---------------- QKV 1x1 conv (channel GEMM), f32, outputs bf16 [h][d][n] ----------------
// grid (64, 32), block 256: o = by*4 + wave, n = bx*64 + lane.
__global__ __launch_bounds__(256) void qkv_k(const float* __restrict__ h,
                                             const float* __restrict__ qw, const float* __restrict__ qb,
                                             const float* __restrict__ kw, const float* __restrict__ kb,
                                             const float* __restrict__ vw, const float* __restrict__ vb,
                                             unsigned short* __restrict__ q,
                                             unsigned short* __restrict__ k,
                                             unsigned short* __restrict__ v) {
  int o = blockIdx.y * 4 + (threadIdx.x >> 6);
  int n = blockIdx.x * 64 + (threadIdx.x & 63);
  const float* __restrict__ qr = qw + o * NCH;   // wave-uniform -> scalar loads
  const float* __restrict__ kr = kw + o * NCH;
  const float* __restrict__ vr = vw + o * NCH;
  float aq = qb[o], ak = kb[o], av = vb[o];
#pragma unroll 8
  for (int c = 0; c < NCH; c++) {
    float hv = h[c * NPOS + n];
    aq += qr[c] * hv;
    ak += kr[c] * hv;
    av += vr[c] * hv;
  }
  q[o * NPOS + n] = f2bf(aq);
  k[o * NPOS + n] = f2bf(ak);
  v[o * NPOS + n] = f2bf(av);
}

// ---------------- Flash attention, bf16 MFMA 16x16x32 ----------------
// grid 256 = 4 heads x 64 q-tiles(64 queries). 4 waves/block, 16 queries each.
// q,k,v: [head][d=32][n=4096] bf16.  Out: At[c=128][n=4096] f32 (c = head*32+d).
__global__ __launch_bounds__(256) void attn_k(const unsigned short* __restrict__ q,
                                              const unsigned short* __restrict__ k,
                                              const unsigned short* __restrict__ v,
                                              float* __restrict__ At) {
  const int head = blockIdx.x >> 6;
  const int q0   = (blockIdx.x & 63) * 64;
  const int t    = threadIdx.x;
  const int w    = t >> 6;          // wave 0..3
  const int lane = t & 63;
  const int l16  = lane & 15;
  const int quad = lane >> 4;

  __shared__ __align__(16) unsigned short k_lds[32][72];      // [d][key], +pad
  __shared__ __align__(16) unsigned short v_lds[32][72];      // [d][key], +pad
  __shared__ __align__(16) unsigned short p_lds[4][16][72];   // per-wave P [q][key]

  // Q fragment (A-layout): A[m=l16][kk=quad*8+j], persistent for the block.
  short8 aq;
  {
    const unsigned short* qp = q + (size_t)(head * DH + quad * 8) * NPOS + (q0 + w * 16 + l16);
#pragma unroll
    for (int j = 0; j < 8; j++) aq[j] = (short)qp[j * NPOS];
  }

  floatx4 o0 = {0.f, 0.f, 0.f, 0.f};
  floatx4 o1 = {0.f, 0.f, 0.f, 0.f};
  float m_r[4], l_r[4];
#pragma unroll
  for (int r = 0; r < 4; r++) { m_r[r] = -3.0e38f; l_r[r] = 0.f; }

  const int sd = t >> 3, sseg = t & 7;                 // staging: 32 d-rows x 8 16B-segs
  const unsigned short* kbase = k + (size_t)(head * DH + sd) * NPOS + sseg * 8;
  const unsigned short* vbase = v + (size_t)(head * DH + sd) * NPOS + sseg * 8;
  const float scale = 0.17677669529663687f;            // 32^-0.5
  const floatx4 zero = {0.f, 0.f, 0.f, 0.f};

  for (int m0 = 0; m0 < NPOS; m0 += 64) {
    __syncthreads();
    *(short8*)&k_lds[sd][sseg * 8] = *(const short8*)(kbase + m0);
    *(short8*)&v_lds[sd][sseg * 8] = *(const short8*)(vbase + m0);
    __syncthreads();

    // S = Q K^T : 4 subtiles of 16 keys
    floatx4 c[4];
#pragma unroll
    for (int sub = 0; sub < 4; sub++) {
      short8 bk;
#pragma unroll
      for (int j = 0; j < 8; j++) bk[j] = (short)k_lds[quad * 8 + j][sub * 16 + l16];
      c[sub] = __builtin_amdgcn_mfma_f32_16x16x32_bf16(aq, bk, zero, 0, 0, 0);
    }

    // online softmax per row (row = quad*4 + r, cols across l16 within quad group)
#pragma unroll
    for (int r = 0; r < 4; r++) {
      float s0 = c[0][r] * scale, s1 = c[1][r] * scale;
      float s2 = c[2][r] * scale, s3 = c[3][r] * scale;
      float mx = fmaxf(fmaxf(s0, s1), fmaxf(s2, s3));
#pragma unroll
      for (int m = 1; m < 16; m <<= 1) mx = fmaxf(mx, __shfl_xor(mx, m));
      float mn = fmaxf(m_r[r], mx);
      float alpha = __expf(m_r[r] - mn);
      float p0 = __expf(s0 - mn), p1 = __expf(s1 - mn);
      float p2 = __expf(s2 - mn), p3 = __expf(s3 - mn);
      int row = quad * 4 + r;
      p_lds[w][row][ 0 + l16] = f2bf(p0);
      p_lds[w][row][16 + l16] = f2bf(p1);
      p_lds[w][row][32 + l16] = f2bf(p2);
      p_lds[w][row][48 + l16] = f2bf(p3);
      float rs = p0 + p1 + p2 + p3;
#pragma unroll
      for (int m = 1; m < 16; m <<= 1) rs += __shfl_xor(rs, m);
      l_r[r] = l_r[r] * alpha + rs;
      m_r[r] = mn;
      o0[r] *= alpha;
      o1[r] *= alpha;
    }

    // O += P V^T : P in A-layout from LDS, V^T in B-layout (n = d)
#pragma unroll
    for (int kc = 0; kc < 2; kc++) {
      short8 pa  = *(const short8*)&p_lds[w][l16][kc * 32 + quad * 8];
      short8 bv0 = *(const short8*)&v_lds[l16     ][kc * 32 + quad * 8];
      short8 bv1 = *(const short8*)&v_lds[16 + l16][kc * 32 + quad * 8];
      o0 = __builtin_amdgcn_mfma_f32_16x16x32_bf16(pa, bv0, o0, 0, 0, 0);
      o1 = __builtin_amdgcn_mfma_f32_16x16x32_bf16(pa, bv1, o1, 0, 0, 0);
    }
  }

  // epilogue: O /= l ; store At[c][n] (rows r are consecutive n -> float4)
  int nn = q0 + w * 16 + quad * 4;
  int c0 = head * DH + l16;
  float4 r0, r1;
  r0.x = o0[0] / l_r[0]; r0.y = o0[1] / l_r[1]; r0.z = o0[2] / l_r[2]; r0.w = o0[3] / l_r[3];
  r1.x = o1[0] / l_r[0]; r1.y = o1[1] / l_r[1]; r1.z = o1[2] / l_r[2]; r1.w = o1[3] / l_r[3];
  *(float4*)(At + (size_t)c0 * NPOS + nn)        = r0;
  *(float4*)(At + (size_t)(c0 + 16) * NPOS + nn) = r1;
}

// ---------------- proj 1x1 conv + residual ----------------
__global__ __launch_bounds__(256) void proj_k(const float* __restrict__ At,
                                              const float* __restrict__ pw,
                                              const float* __restrict__ pb,
                                              const float* __restrict__ x,
                                              float* __restrict__ out) {
  int o = blockIdx.y * 4 + (threadIdx.x >> 6);
  int n = blockIdx.x * 64 + (threadIdx.x & 63);
  const float* __restrict__ pr = pw + o * NCH;
  float acc = pb[o];
#pragma unroll 8
  for (int c = 0; c < NCH; c++) acc += pr[c] * At[c * NPOS + n];
  out[o * NPOS + n] = acc + x[o * NPOS + n];
}

extern "C" void kernel_launch(void* const* d_in, const int* in_sizes, int n_in,
                              void* d_out, int out_size, void* d_ws, size_t ws_size,
                              hipStream_t stream) {
  const float* x   = (const float*)d_in[0];
  const float* gnw = (const float*)d_in[1];
  const float* gnb = (const float*)d_in[2];
  const float* qw  = (const float*)d_in[3];
  const float* qb  = (const float*)d_in[4];
  const float* kw  = (const float*)d_in[5];
  const float* kb  = (const float*)d_in[6];
  const float* vw  = (const float*)d_in[7];
  const float* vb  = (const float*)d_in[8];
  const float* pw  = (const float*)d_in[9];
  const float* pb  = (const float*)d_in[10];
  float* out = (float*)d_out;

  // workspace layout
  float* ws    = (float*)d_ws;
  float* stats = ws;                       // 2 floats (padded to 64)
  float* h     = ws + 64;                  // 524288 f32
  float* At    = ws + 64 + NTOT;           // 524288 f32
  unsigned short* qbuf = (unsigned short*)(ws + 64 + 2 * NTOT);  // 524288 bf16
  unsigned short* kbuf = qbuf + NTOT;
  unsigned short* vbuf = kbuf + NTOT;

  hipMemsetAsync(d_ws, 0, 8, stream);      // zero stats (ws is poisoned each call)

  gn_reduce_k<<<256, 256, 0, stream>>>(x, stats);
  gn_norm_k<<<512, 256, 0, stream>>>(x, gnw, gnb, stats, h);
  qkv_k<<<dim3(64, 32), 256, 0, stream>>>(h, qw, qb, kw, kb, vw, vb, qbuf, kbuf, vbuf);
  attn_k<<<256, 256, 0, stream>>>(qbuf, kbuf, vbuf, At);
  proj_k<<<dim3(64, 32), 256, 0, stream>>>(At, pw, pb, x, out);
}

// Round 2
// 177.592 us; speedup vs baseline: 1.4579x; 1.4579x over previous
//
#include <hip/hip_runtime.h>

#define NPOS 4096
#define NCH  128
#define NTOT (NPOS * NCH)   // 524288
#define NHEAD 4
#define DH    32

typedef __attribute__((ext_vector_type(8))) short short8;   // 8 bf16
typedef __attribute__((ext_vector_type(4))) float floatx4;  // MFMA acc
typedef unsigned short u16;
typedef unsigned int   u32;

__device__ __forceinline__ u16 f2bf(float f) {              // RNE
  u32 u = __float_as_uint(f);
  u += 0x7fffu + ((u >> 16) & 1u);
  return (u16)(u >> 16);
}
__device__ __forceinline__ u32 pack2bf(float a, float b) {
  return (u32)f2bf(a) | ((u32)f2bf(b) << 16);
}
__device__ __forceinline__ u16 f2bf_fast(float f) {         // round-half-up, 2 ops
  return (u16)((__float_as_uint(f) + 0x8000u) >> 16);
}
__device__ __forceinline__ float bf2f(u16 h) {
  return __uint_as_float(((u32)h) << 16);
}

// ---------------- GroupNorm pass 1: global sum/sumsq ----------------
__global__ __launch_bounds__(256) void gn_reduce_k(const float* __restrict__ x,
                                                   float* __restrict__ stats) {
  int i = blockIdx.x * 256 + threadIdx.x;           // 0..65535
  float4 a = ((const float4*)x)[i];
  float4 b = ((const float4*)x)[i + 65536];
  float s  = a.x + a.y + a.z + a.w + b.x + b.y + b.z + b.w;
  float sq = a.x*a.x + a.y*a.y + a.z*a.z + a.w*a.w
           + b.x*b.x + b.y*b.y + b.z*b.z + b.w*b.w;
#pragma unroll
  for (int m = 1; m < 64; m <<= 1) {
    s  += __shfl_xor(s, m);
    sq += __shfl_xor(sq, m);
  }
  if ((threadIdx.x & 63) == 0) {
    atomicAdd(&stats[0], s);
    atomicAdd(&stats[1], sq);
  }
}

// ---------------- weight prep: f32 -> bf16 (q scaled by scale*log2e) ----------------
__global__ __launch_bounds__(256) void wprep_k(const float* __restrict__ qw, const float* __restrict__ kw,
                                               const float* __restrict__ vw, const float* __restrict__ pw,
                                               u16* __restrict__ wq, u16* __restrict__ wk,
                                               u16* __restrict__ wv, u16* __restrict__ wp) {
  int t = blockIdx.x * 256 + threadIdx.x;   // 0..4095 (float4 index into 128x128)
  const float sc = 0.17677669529663687f * 1.4426950408889634f;  // d^-0.5 * log2(e)
  float4 a = ((const float4*)qw)[t];
  ((uint2*)wq)[t] = make_uint2(pack2bf(a.x*sc, a.y*sc), pack2bf(a.z*sc, a.w*sc));
  a = ((const float4*)kw)[t];
  ((uint2*)wk)[t] = make_uint2(pack2bf(a.x, a.y), pack2bf(a.z, a.w));
  a = ((const float4*)vw)[t];
  ((uint2*)wv)[t] = make_uint2(pack2bf(a.x, a.y), pack2bf(a.z, a.w));
  a = ((const float4*)pw)[t];
  ((uint2*)wp)[t] = make_uint2(pack2bf(a.x, a.y), pack2bf(a.z, a.w));
}

// ---------------- GroupNorm pass 2 + transpose: h[n][c] bf16 ----------------
__global__ __launch_bounds__(256) void gn_norm_k(const float* __restrict__ x,
                                                 const float* __restrict__ gw,
                                                 const float* __restrict__ gb,
                                                 const float* __restrict__ stats,
                                                 u16* __restrict__ h) {
  int i = blockIdx.x * 256 + threadIdx.x;      // 0..65535
  int n = i & (NPOS - 1), cg = i >> 12;        // cg 0..15 (uniform per block)
  int c0 = cg * 8;
  float mean = stats[0] * (1.0f / NTOT);
  float var  = stats[1] * (1.0f / NTOT) - mean * mean;
  float rstd = rsqrtf(var + 1e-5f);
  float vals[8];
#pragma unroll
  for (int j = 0; j < 8; j++) {
    int c = c0 + j;
    float sw = gw[c] * rstd;
    float sb = gb[c] - mean * sw;
    vals[j] = x[(size_t)c * NPOS + n] * sw + sb;
  }
  uint4 o;
  o.x = pack2bf(vals[0], vals[1]);
  o.y = pack2bf(vals[2], vals[3]);
  o.z = pack2bf(vals[4], vals[5]);
  o.w = pack2bf(vals[6], vals[7]);
  *(uint4*)(h + (size_t)n * NCH + c0) = o;     // 16B contiguous per thread
}

// ---------------- fused QKV GEMM (MFMA), outputs q,k [h][n][d], v [h][d][n] ----------------
// grid 256 blocks x 256 thr; wave w owns o-range [32w,32w+32) == head w; n-tile 16.
__global__ __launch_bounds__(256) void qkv_k(const u16* __restrict__ h,
    const u16* __restrict__ wq, const u16* __restrict__ wk, const u16* __restrict__ wv,
    const float* __restrict__ qb, const float* __restrict__ kb, const float* __restrict__ vb,
    u16* __restrict__ q, u16* __restrict__ k, u16* __restrict__ v, u32* __restrict__ bounds) {
  const int w = threadIdx.x >> 6, lane = threadIdx.x & 63;
  const int l16 = lane & 15, quad = lane >> 4;
  const int n0 = blockIdx.x * 16, ow = w * 32;
  const int n = n0 + l16;
  const floatx4 zero = {0.f, 0.f, 0.f, 0.f};

  short8 bfr[4];                                 // B-frags: h[n][c], reused x3
  const u16* hp = h + (size_t)n * NCH + quad * 8;
#pragma unroll
  for (int kk = 0; kk < 4; kk++) bfr[kk] = *(const short8*)(hp + kk * 32);

  // ---- Q (scale*log2e folded into weights; bias scaled here)
  {
    floatx4 a0 = zero, a1 = zero;
    const u16* ap = wq + (size_t)(ow + l16) * NCH + quad * 8;
#pragma unroll
    for (int kk = 0; kk < 4; kk++) {
      a0 = __builtin_amdgcn_mfma_f32_16x16x32_bf16(*(const short8*)(ap + kk*32),          bfr[kk], a0, 0,0,0);
      a1 = __builtin_amdgcn_mfma_f32_16x16x32_bf16(*(const short8*)(ap + 16*NCH + kk*32), bfr[kk], a1, 0,0,0);
    }
    const float sc = 0.17677669529663687f * 1.4426950408889634f;
    u16* qp = q + (size_t)(w * NPOS + n) * DH;
#pragma unroll
    for (int s = 0; s < 2; s++) {
      floatx4 acc = s ? a1 : a0;
      int od = s * 16 + quad * 4;
      float r0 = acc[0] + qb[ow+od+0]*sc, r1 = acc[1] + qb[ow+od+1]*sc;
      float r2 = acc[2] + qb[ow+od+2]*sc, r3 = acc[3] + qb[ow+od+3]*sc;
      *(uint2*)(qp + od) = make_uint2(pack2bf(r0, r1), pack2bf(r2, r3));
    }
  }
  // ---- K (+ per-head max ||k||^2 for the softmax bound)
  {
    floatx4 a0 = zero, a1 = zero;
    const u16* ap = wk + (size_t)(ow + l16) * NCH + quad * 8;
#pragma unroll
    for (int kk = 0; kk < 4; kk++) {
      a0 = __builtin_amdgcn_mfma_f32_16x16x32_bf16(*(const short8*)(ap + kk*32),          bfr[kk], a0, 0,0,0);
      a1 = __builtin_amdgcn_mfma_f32_16x16x32_bf16(*(const short8*)(ap + 16*NCH + kk*32), bfr[kk], a1, 0,0,0);
    }
    float sumsq = 0.f;
    u16* kp = k + (size_t)(w * NPOS + n) * DH;
#pragma unroll
    for (int s = 0; s < 2; s++) {
      floatx4 acc = s ? a1 : a0;
      int od = s * 16 + quad * 4;
      float r0 = acc[0] + kb[ow+od+0], r1 = acc[1] + kb[ow+od+1];
      float r2 = acc[2] + kb[ow+od+2], r3 = acc[3] + kb[ow+od+3];
      sumsq += r0*r0 + r1*r1 + r2*r2 + r3*r3;
      *(uint2*)(kp + od) = make_uint2(pack2bf(r0, r1), pack2bf(r2, r3));
    }
    sumsq += __shfl_xor(sumsq, 16);              // sum over quads -> ||k_n||^2
    sumsq += __shfl_xor(sumsq, 32);
#pragma unroll
    for (int m = 1; m < 16; m <<= 1) sumsq = fmaxf(sumsq, __shfl_xor(sumsq, m));
    if (lane == 0) atomicMax(&bounds[w], __float_as_uint(sumsq));  // positive f32: bit-order ok
  }
  // ---- V
  {
    floatx4 a0 = zero, a1 = zero;
    const u16* ap = wv + (size_t)(ow + l16) * NCH + quad * 8;
#pragma unroll
    for (int kk = 0; kk < 4; kk++) {
      a0 = __builtin_amdgcn_mfma_f32_16x16x32_bf16(*(const short8*)(ap + kk*32),          bfr[kk], a0, 0,0,0);
      a1 = __builtin_amdgcn_mfma_f32_16x16x32_bf16(*(const short8*)(ap + 16*NCH + kk*32), bfr[kk], a1, 0,0,0);
    }
    u16* vp = v + (size_t)(w * DH) * NPOS + n;
#pragma unroll
    for (int s = 0; s < 2; s++) {
      floatx4 acc = s ? a1 : a0;
      int od = s * 16 + quad * 4;
#pragma unroll
      for (int r = 0; r < 4; r++)
        vp[(size_t)(od + r) * NPOS] = f2bf(acc[r] + vb[ow + od + r]);
    }
  }
}

// ---------------- flash attention: 1 wave / 16 queries, barrier-free ----------------
// grid 1024 x 64. q,k [h][n][d]; v [h][d][n]; At out [n][c] bf16.
// Softmax uses fixed bound s <= |q|*kmax (Cauchy-Schwarz): no running max/rescale.
// Row sums via MFMA against ones-fragment.
__global__ __launch_bounds__(64) void attn_k(const u16* __restrict__ q, const u16* __restrict__ k,
                                             const u16* __restrict__ v, const u32* __restrict__ bounds,
                                             u16* __restrict__ At) {
  const int head = blockIdx.x >> 8;
  const int qb0  = (blockIdx.x & 255) * 16;
  const int lane = threadIdx.x & 63;
  const int l16 = lane & 15, quad = lane >> 4;
  __shared__ u16 p_lds[16][72];                  // P transpose round-trip (C->A layout)

  short8 aq = *(const short8*)(q + (size_t)(head * NPOS + qb0 + l16) * DH + quad * 8);
  float qn2 = 0.f;
#pragma unroll
  for (int j = 0; j < 8; j++) { float f = bf2f((u16)aq[j]); qn2 += f * f; }
  qn2 += __shfl_xor(qn2, 16);
  qn2 += __shfl_xor(qn2, 32);                    // every lane: ||q_{l16}||^2 (scaled domain)
  float kmax = sqrtf(__uint_as_float(bounds[head])) * 1.0005f;
  float bound[4];
#pragma unroll
  for (int r = 0; r < 4; r++) bound[r] = sqrtf(__shfl(qn2, quad * 4 + r)) * kmax;

  floatx4 o0 = {0,0,0,0}, o1 = {0,0,0,0}, ol = {0,0,0,0};
  short8 ones;
#pragma unroll
  for (int j = 0; j < 8; j++) ones[j] = (short)0x3F80;   // bf16 1.0

  const u16* kbp = k + (size_t)head * NPOS * DH;
  const u16* vb0 = v + (size_t)(head * DH + l16) * NPOS;
  const u16* vb1 = v + (size_t)(head * DH + 16 + l16) * NPOS;
  const floatx4 zero = {0,0,0,0};

  for (int m0 = 0; m0 < NPOS; m0 += 64) {
    floatx4 c[4];
#pragma unroll
    for (int sub = 0; sub < 4; sub++) {
      short8 bk = *(const short8*)(kbp + (size_t)(m0 + sub*16 + l16) * DH + quad * 8);
      c[sub] = __builtin_amdgcn_mfma_f32_16x16x32_bf16(aq, bk, zero, 0, 0, 0);
    }
#pragma unroll
    for (int r = 0; r < 4; r++) {
      int row = quad * 4 + r;
      p_lds[row][ 0 + l16] = f2bf_fast(__builtin_amdgcn_exp2f(c[0][r] - bound[r]));
      p_lds[row][16 + l16] = f2bf_fast(__builtin_amdgcn_exp2f(c[1][r] - bound[r]));
      p_lds[row][32 + l16] = f2bf_fast(__builtin_amdgcn_exp2f(c[2][r] - bound[r]));
      p_lds[row][48 + l16] = f2bf_fast(__builtin_amdgcn_exp2f(c[3][r] - bound[r]));
    }
#pragma unroll
    for (int kc = 0; kc < 2; kc++) {
      short8 pa  = *(const short8*)&p_lds[l16][kc * 32 + quad * 8];
      short8 bv0 = *(const short8*)(vb0 + m0 + kc * 32 + quad * 8);
      short8 bv1 = *(const short8*)(vb1 + m0 + kc * 32 + quad * 8);
      o0 = __builtin_amdgcn_mfma_f32_16x16x32_bf16(pa, bv0, o0, 0, 0, 0);
      o1 = __builtin_amdgcn_mfma_f32_16x16x32_bf16(pa, bv1, o1, 0, 0, 0);
      ol = __builtin_amdgcn_mfma_f32_16x16x32_bf16(pa, ones, ol, 0, 0, 0);
    }
  }
#pragma unroll
  for (int r = 0; r < 4; r++) {
    float inv = 1.0f / fmaxf(ol[r], 1e-35f);
    int nn = qb0 + quad * 4 + r;
    At[(size_t)nn * NCH + head * DH + l16]      = f2bf(o0[r] * inv);
    At[(size_t)nn * NCH + head * DH + 16 + l16] = f2bf(o1[r] * inv);
  }
}

// ---------------- proj GEMM (MFMA) + bias + residual, f32 out [c][n] ----------------
__global__ __launch_bounds__(256) void proj_k(const u16* __restrict__ At, const u16* __restrict__ wp,
                                              const float* __restrict__ pb, const float* __restrict__ x,
                                              float* __restrict__ out) {
  const int w = threadIdx.x >> 6, lane = threadIdx.x & 63;
  const int l16 = lane & 15, quad = lane >> 4;
  const int n0 = blockIdx.x * 16, ow = w * 32;
  const int n = n0 + l16;
  const floatx4 zero = {0.f, 0.f, 0.f, 0.f};
  short8 bfr[4];
  const u16* apn = At + (size_t)n * NCH + quad * 8;
#pragma unroll
  for (int kk = 0; kk < 4; kk++) bfr[kk] = *(const short8*)(apn + kk * 32);
  floatx4 a0 = zero, a1 = zero;
  const u16* ap = wp + (size_t)(ow + l16) * NCH + quad * 8;
#pragma unroll
  for (int kk = 0; kk < 4; kk++) {
    a0 = __builtin_amdgcn_mfma_f32_16x16x32_bf16(*(const short8*)(ap + kk*32),          bfr[kk], a0, 0,0,0);
    a1 = __builtin_amdgcn_mfma_f32_16x16x32_bf16(*(const short8*)(ap + 16*NCH + kk*32), bfr[kk], a1, 0,0,0);
  }
#pragma unroll
  for (int s = 0; s < 2; s++) {
    floatx4 acc = s ? a1 : a0;
    int o = ow + s * 16 + quad * 4;
#pragma unroll
    for (int r = 0; r < 4; r++) {
      size_t idx = (size_t)(o + r) * NPOS + n;
      out[idx] = acc[r] + pb[o + r] + x[idx];
    }
  }
}

extern "C" void kernel_launch(void* const* d_in, const int* in_sizes, int n_in,
                              void* d_out, int out_size, void* d_ws, size_t ws_size,
                              hipStream_t stream) {
  const float* x   = (const float*)d_in[0];
  const float* gnw = (const float*)d_in[1];
  const float* gnb = (const float*)d_in[2];
  const float* qw  = (const float*)d_in[3];
  const float* qb  = (const float*)d_in[4];
  const float* kw  = (const float*)d_in[5];
  const float* kb  = (const float*)d_in[6];
  const float* vw  = (const float*)d_in[7];
  const float* vb  = (const float*)d_in[8];
  const float* pw  = (const float*)d_in[9];
  const float* pb  = (const float*)d_in[10];
  float* out = (float*)d_out;

  float* ws    = (float*)d_ws;
  float* stats = ws;                               // 2 f32
  u32*   bounds = (u32*)(ws + 4);                  // 4 u32 (per-head max ||k||^2)
  u16* wqb = (u16*)(ws + 64);                      // 4 x 16384 bf16
  u16* wkb = wqb + 16384;
  u16* wvb = wkb + 16384;
  u16* wpb = wvb + 16384;
  u16* hbuf = (u16*)(ws + 64 + 32768 / 2 * 2 + 0); // = ws + 64 + 32768/... computed below
  hbuf = wpb + 16384;                              // h [n][c] bf16, 524288
  u16* qbuf = hbuf + NTOT;                         // [h][n][d]
  u16* kbuf = qbuf + NTOT;                         // [h][n][d]
  u16* vbuf = kbuf + NTOT;                         // [h][d][n]
  u16* Atb  = vbuf + NTOT;                         // [n][c]

  hipMemsetAsync(d_ws, 0, 256, stream);            // stats + bounds

  gn_reduce_k<<<256, 256, 0, stream>>>(x, stats);
  wprep_k<<<16, 256, 0, stream>>>(qw, kw, vw, pw, wqb, wkb, wvb, wpb);
  gn_norm_k<<<256, 256, 0, stream>>>(x, gnw, gnb, stats, hbuf);
  qkv_k<<<256, 256, 0, stream>>>(hbuf, wqb, wkb, wvb, qb, kb, vb, qbuf, kbuf, vbuf, bounds);
  attn_k<<<1024, 64, 0, stream>>>(qbuf, kbuf, vbuf, bounds, Atb);
  proj_k<<<256, 256, 0, stream>>>(Atb, wpb, pb, x, out);
}

// Round 3
// 172.434 us; speedup vs baseline: 1.5015x; 1.0299x over previous
//
#include <hip/hip_runtime.h>

#define NPOS 4096
#define NCH  128
#define NTOT (NPOS * NCH)   // 524288
#define NHEAD 4
#define DH    32

typedef __attribute__((ext_vector_type(8))) short short8;   // 8 bf16
typedef __attribute__((ext_vector_type(4))) float floatx4;  // MFMA acc
typedef unsigned short u16;
typedef unsigned int   u32;

__device__ __forceinline__ u16 f2bf(float f) {              // RNE
  u32 u = __float_as_uint(f);
  u += 0x7fffu + ((u >> 16) & 1u);
  return (u16)(u >> 16);
}
__device__ __forceinline__ u32 pack2bf(float a, float b) {
  return (u32)f2bf(a) | ((u32)f2bf(b) << 16);
}
__device__ __forceinline__ u32 pack2bf_fast(float a, float b) {  // round-half-up
  return ((__float_as_uint(a) + 0x8000u) >> 16) |
         ((__float_as_uint(b) + 0x8000u) & 0xffff0000u);
}
__device__ __forceinline__ float bf2f(u16 h) {
  return __uint_as_float(((u32)h) << 16);
}

// ---------------- GroupNorm reduce + weight bf16 prep (fused) ----------------
__global__ __launch_bounds__(256) void gn_prep_k(const float* __restrict__ x,
                                                 float* __restrict__ stats,
                                                 const float* __restrict__ qw, const float* __restrict__ kw,
                                                 const float* __restrict__ vw, const float* __restrict__ pw,
                                                 u16* __restrict__ wq, u16* __restrict__ wk,
                                                 u16* __restrict__ wv, u16* __restrict__ wp) {
  int i = blockIdx.x * 256 + threadIdx.x;           // 0..65535
  float4 a = ((const float4*)x)[i];
  float4 b = ((const float4*)x)[i + 65536];
  float s  = a.x + a.y + a.z + a.w + b.x + b.y + b.z + b.w;
  float sq = a.x*a.x + a.y*a.y + a.z*a.z + a.w*a.w
           + b.x*b.x + b.y*b.y + b.z*b.z + b.w*b.w;
#pragma unroll
  for (int m = 1; m < 64; m <<= 1) {
    s  += __shfl_xor(s, m);
    sq += __shfl_xor(sq, m);
  }
  if ((threadIdx.x & 63) == 0) {
    atomicAdd(&stats[0], s);
    atomicAdd(&stats[1], sq);
  }
  if (blockIdx.x < 16) {
    int t = blockIdx.x * 256 + threadIdx.x;         // 0..4095 float4 idx into 128x128
    const float sc = 0.17677669529663687f * 1.4426950408889634f;  // d^-0.5 * log2e
    float4 v = ((const float4*)qw)[t];
    ((uint2*)wq)[t] = make_uint2(pack2bf(v.x*sc, v.y*sc), pack2bf(v.z*sc, v.w*sc));
    v = ((const float4*)kw)[t];
    ((uint2*)wk)[t] = make_uint2(pack2bf(v.x, v.y), pack2bf(v.z, v.w));
    v = ((const float4*)vw)[t];
    ((uint2*)wv)[t] = make_uint2(pack2bf(v.x, v.y), pack2bf(v.z, v.w));
    v = ((const float4*)pw)[t];
    ((uint2*)wp)[t] = make_uint2(pack2bf(v.x, v.y), pack2bf(v.z, v.w));
  }
}

// ---------------- fused GN-normalize + QKV GEMM (MFMA) ----------------
// grid 256; wave w = head w (o-rows 32w..32w+31); n-tile 16 per block.
// q,k out [h][n][d]; v out [h][d][n]; bounds[h] = max ||k_n||^2.
__global__ __launch_bounds__(256) void qkv_k(const float* __restrict__ x,
    const float* __restrict__ gw, const float* __restrict__ gb, const float* __restrict__ stats,
    const u16* __restrict__ wq, const u16* __restrict__ wk, const u16* __restrict__ wv,
    const float* __restrict__ qb, const float* __restrict__ kb, const float* __restrict__ vb,
    u16* __restrict__ q, u16* __restrict__ k, u16* __restrict__ v, u32* __restrict__ bounds) {
  const int w = threadIdx.x >> 6, lane = threadIdx.x & 63;
  const int l16 = lane & 15, quad = lane >> 4;
  const int n0 = blockIdx.x * 16, ow = w * 32;
  const int n = n0 + l16;
  const floatx4 zero = {0.f, 0.f, 0.f, 0.f};

  float mean = stats[0] * (1.0f / NTOT);
  float var  = stats[1] * (1.0f / NTOT) - mean * mean;
  float rstd = rsqrtf(var + 1e-5f);

  short8 bfr[4];                                 // GN'd h[n][c] B-frags, built from x
#pragma unroll
  for (int kk = 0; kk < 4; kk++) {
    u32 pk[4];
#pragma unroll
    for (int jj = 0; jj < 4; jj++) {
      int c = kk * 32 + quad * 8 + jj * 2;
      float sw0 = gw[c] * rstd,     sb0 = gb[c] - mean * sw0;
      float sw1 = gw[c + 1] * rstd, sb1 = gb[c + 1] - mean * sw1;
      float v0 = x[(size_t)c * NPOS + n] * sw0 + sb0;
      float v1 = x[(size_t)(c + 1) * NPOS + n] * sw1 + sb1;
      pk[jj] = pack2bf(v0, v1);
    }
    uint4 u = make_uint4(pk[0], pk[1], pk[2], pk[3]);
    bfr[kk] = *(short8*)&u;
  }

  // ---- Q (scale*log2e folded into weights; bias scaled here)
  {
    floatx4 a0 = zero, a1 = zero;
    const u16* ap = wq + (size_t)(ow + l16) * NCH + quad * 8;
#pragma unroll
    for (int kk = 0; kk < 4; kk++) {
      a0 = __builtin_amdgcn_mfma_f32_16x16x32_bf16(*(const short8*)(ap + kk*32),          bfr[kk], a0, 0,0,0);
      a1 = __builtin_amdgcn_mfma_f32_16x16x32_bf16(*(const short8*)(ap + 16*NCH + kk*32), bfr[kk], a1, 0,0,0);
    }
    const float sc = 0.17677669529663687f * 1.4426950408889634f;
    u16* qp = q + (size_t)(w * NPOS + n) * DH;
#pragma unroll
    for (int s = 0; s < 2; s++) {
      floatx4 acc = s ? a1 : a0;
      int od = s * 16 + quad * 4;
      float r0 = acc[0] + qb[ow+od+0]*sc, r1 = acc[1] + qb[ow+od+1]*sc;
      float r2 = acc[2] + qb[ow+od+2]*sc, r3 = acc[3] + qb[ow+od+3]*sc;
      *(uint2*)(qp + od) = make_uint2(pack2bf(r0, r1), pack2bf(r2, r3));
    }
  }
  // ---- K (+ per-head max ||k||^2)
  {
    floatx4 a0 = zero, a1 = zero;
    const u16* ap = wk + (size_t)(ow + l16) * NCH + quad * 8;
#pragma unroll
    for (int kk = 0; kk < 4; kk++) {
      a0 = __builtin_amdgcn_mfma_f32_16x16x32_bf16(*(const short8*)(ap + kk*32),          bfr[kk], a0, 0,0,0);
      a1 = __builtin_amdgcn_mfma_f32_16x16x32_bf16(*(const short8*)(ap + 16*NCH + kk*32), bfr[kk], a1, 0,0,0);
    }
    float sumsq = 0.f;
    u16* kp = k + (size_t)(w * NPOS + n) * DH;
#pragma unroll
    for (int s = 0; s < 2; s++) {
      floatx4 acc = s ? a1 : a0;
      int od = s * 16 + quad * 4;
      float r0 = acc[0] + kb[ow+od+0], r1 = acc[1] + kb[ow+od+1];
      float r2 = acc[2] + kb[ow+od+2], r3 = acc[3] + kb[ow+od+3];
      sumsq += r0*r0 + r1*r1 + r2*r2 + r3*r3;
      *(uint2*)(kp + od) = make_uint2(pack2bf(r0, r1), pack2bf(r2, r3));
    }
    sumsq += __shfl_xor(sumsq, 16);
    sumsq += __shfl_xor(sumsq, 32);
#pragma unroll
    for (int m = 1; m < 16; m <<= 1) sumsq = fmaxf(sumsq, __shfl_xor(sumsq, m));
    if (lane == 0) atomicMax(&bounds[w], __float_as_uint(sumsq));
  }
  // ---- V
  {
    floatx4 a0 = zero, a1 = zero;
    const u16* ap = wv + (size_t)(ow + l16) * NCH + quad * 8;
#pragma unroll
    for (int kk = 0; kk < 4; kk++) {
      a0 = __builtin_amdgcn_mfma_f32_16x16x32_bf16(*(const short8*)(ap + kk*32),          bfr[kk], a0, 0,0,0);
      a1 = __builtin_amdgcn_mfma_f32_16x16x32_bf16(*(const short8*)(ap + 16*NCH + kk*32), bfr[kk], a1, 0,0,0);
    }
    u16* vp = v + (size_t)(w * DH) * NPOS + n;
#pragma unroll
    for (int s = 0; s < 2; s++) {
      floatx4 acc = s ? a1 : a0;
      int od = s * 16 + quad * 4;
#pragma unroll
      for (int r = 0; r < 4; r++)
        vp[(size_t)(od + r) * NPOS] = f2bf(acc[r] + vb[ow + od + r]);
    }
  }
}

// ---------------- flash attention, S^T form, 2-way split-K ----------------
// grid 512 x 256: block b -> (split s = b>>8, qtile = b&255); wave w = head.
// Per wave: 16 queries, keys [s*2048, s*2048+2048).
// Outputs UNNORMALIZED partials: Opart[s][h][q][d] f32, lpart[s][h][q] f32.
__global__ __launch_bounds__(256) void attn_k(const u16* __restrict__ q, const u16* __restrict__ k,
                                              const u16* __restrict__ v, const u32* __restrict__ bounds,
                                              float* __restrict__ Opart, float* __restrict__ lpart) {
  const int w = threadIdx.x >> 6, lane = threadIdx.x & 63;
  const int l16 = lane & 15, quad = lane >> 4;
  const int s = blockIdx.x >> 8;
  const int q0 = (blockIdx.x & 255) * 16;
  const int head = w;
  __shared__ __align__(16) u16 p_lds[4][16][72];   // per-wave P^T->A staging

  // Q B-frag: B[k=d=quad*8+j][n=query=l16]
  short8 bq = *(const short8*)(q + (size_t)(head * NPOS + q0 + l16) * DH + quad * 8);
  float qn2 = 0.f;
#pragma unroll
  for (int j = 0; j < 8; j++) { float f = bf2f((u16)bq[j]); qn2 += f * f; }
  qn2 += __shfl_xor(qn2, 16);
  qn2 += __shfl_xor(qn2, 32);                      // ||q_{l16}||^2 (scaled domain)
  float kmax = sqrtf(__uint_as_float(bounds[head])) * 1.0005f;
  float bound = sqrtf(qn2) * kmax;                 // per query l16: uniform over regs

  floatx4 o0 = {0,0,0,0}, o1 = {0,0,0,0};
  float lacc = 0.f;
  const u16* kbp = k + (size_t)head * NPOS * DH;
  const u16* vb0 = v + (size_t)(head * DH + l16) * NPOS;
  const u16* vb1 = v + (size_t)(head * DH + 16 + l16) * NPOS;
  const floatx4 zero = {0,0,0,0};

  const int m0beg = s * (NPOS / 2), m0end = m0beg + NPOS / 2;
  for (int m0 = m0beg; m0 < m0end; m0 += 64) {
    // S^T = K Q^T: A[m=key][k=d] contiguous from k[h][n][d]
    floatx4 c[4];
#pragma unroll
    for (int sub = 0; sub < 4; sub++) {
      short8 ak = *(const short8*)(kbp + (size_t)(m0 + sub*16 + l16) * DH + quad * 8);
      c[sub] = __builtin_amdgcn_mfma_f32_16x16x32_bf16(ak, bq, zero, 0, 0, 0);
    }
    // P^T in C-layout: lane holds keys sub*16+quad*4+r at query l16 -> b64 LDS writes
#pragma unroll
    for (int sub = 0; sub < 4; sub++) {
      float p0 = __builtin_amdgcn_exp2f(c[sub][0] - bound);
      float p1 = __builtin_amdgcn_exp2f(c[sub][1] - bound);
      float p2 = __builtin_amdgcn_exp2f(c[sub][2] - bound);
      float p3 = __builtin_amdgcn_exp2f(c[sub][3] - bound);
      lacc += (p0 + p1) + (p2 + p3);
      *(uint2*)&p_lds[w][l16][sub * 16 + quad * 4] =
          make_uint2(pack2bf_fast(p0, p1), pack2bf_fast(p2, p3));
    }
    // O += P V^T: A[m=q=l16][k=key] b128 from LDS; B[k=key][n=d=l16] contiguous from v
#pragma unroll
    for (int kc = 0; kc < 2; kc++) {
      short8 pa  = *(const short8*)&p_lds[w][l16][kc * 32 + quad * 8];
      short8 av0 = *(const short8*)(vb0 + m0 + kc * 32 + quad * 8);
      short8 av1 = *(const short8*)(vb1 + m0 + kc * 32 + quad * 8);
      o0 = __builtin_amdgcn_mfma_f32_16x16x32_bf16(pa, av0, o0, 0, 0, 0);
      o1 = __builtin_amdgcn_mfma_f32_16x16x32_bf16(pa, av1, o1, 0, 0, 0);
    }
  }
  // l: reduce across quads -> full partial row sum for query l16
  lacc += __shfl_xor(lacc, 16);
  lacc += __shfl_xor(lacc, 32);

  float* op = Opart + ((size_t)s * NHEAD + head) * NPOS * DH;
#pragma unroll
  for (int r = 0; r < 4; r++) {
    int qq = q0 + quad * 4 + r;
    op[(size_t)qq * DH + l16]      = o0[r];
    op[(size_t)qq * DH + 16 + l16] = o1[r];
  }
  if (lane < 16)
    lpart[((size_t)s * NHEAD + head) * NPOS + q0 + l16] = lacc;
}

// ---------------- proj GEMM: inline split-combine + bias + residual ----------------
__global__ __launch_bounds__(256) void proj_k(const float* __restrict__ Opart,
                                              const float* __restrict__ lpart,
                                              const u16* __restrict__ wp,
                                              const float* __restrict__ pb,
                                              const float* __restrict__ x,
                                              float* __restrict__ out) {
  const int w = threadIdx.x >> 6, lane = threadIdx.x & 63;
  const int l16 = lane & 15, quad = lane >> 4;
  const int n0 = blockIdx.x * 16, ow = w * 32;
  const int n = n0 + l16;
  const floatx4 zero = {0.f, 0.f, 0.f, 0.f};

  short8 bfr[4];                                   // At[n][c] frags, c-block kk == head kk
#pragma unroll
  for (int kk = 0; kk < 4; kk++) {
    const float* oa = Opart + ((size_t)kk * NPOS + n) * DH + quad * 8;
    const float* ob = oa + (size_t)NHEAD * NPOS * DH;
    float4 a0 = *(const float4*)oa, a1 = *(const float4*)(oa + 4);
    float4 b0 = *(const float4*)ob, b1 = *(const float4*)(ob + 4);
    float l = lpart[(size_t)kk * NPOS + n] + lpart[(size_t)(NHEAD + kk) * NPOS + n];
    float inv = 1.0f / fmaxf(l, 1e-30f);
    uint4 u = make_uint4(pack2bf((a0.x+b0.x)*inv, (a0.y+b0.y)*inv),
                         pack2bf((a0.z+b0.z)*inv, (a0.w+b0.w)*inv),
                         pack2bf((a1.x+b1.x)*inv, (a1.y+b1.y)*inv),
                         pack2bf((a1.z+b1.z)*inv, (a1.w+b1.w)*inv));
    bfr[kk] = *(short8*)&u;
  }
  floatx4 a0 = zero, a1 = zero;
  const u16* ap = wp + (size_t)(ow + l16) * NCH + quad * 8;
#pragma unroll
  for (int kk = 0; kk < 4; kk++) {
    a0 = __builtin_amdgcn_mfma_f32_16x16x32_bf16(*(const short8*)(ap + kk*32),          bfr[kk], a0, 0,0,0);
    a1 = __builtin_amdgcn_mfma_f32_16x16x32_bf16(*(const short8*)(ap + 16*NCH + kk*32), bfr[kk], a1, 0,0,0);
  }
#pragma unroll
  for (int s = 0; s < 2; s++) {
    floatx4 acc = s ? a1 : a0;
    int o = ow + s * 16 + quad * 4;
#pragma unroll
    for (int r = 0; r < 4; r++) {
      size_t idx = (size_t)(o + r) * NPOS + n;
      out[idx] = acc[r] + pb[o + r] + x[idx];
    }
  }
}

extern "C" void kernel_launch(void* const* d_in, const int* in_sizes, int n_in,
                              void* d_out, int out_size, void* d_ws, size_t ws_size,
                              hipStream_t stream) {
  const float* x   = (const float*)d_in[0];
  const float* gnw = (const float*)d_in[1];
  const float* gnb = (const float*)d_in[2];
  const float* qw  = (const float*)d_in[3];
  const float* qb  = (const float*)d_in[4];
  const float* kw  = (const float*)d_in[5];
  const float* kb  = (const float*)d_in[6];
  const float* vw  = (const float*)d_in[7];
  const float* vb  = (const float*)d_in[8];
  const float* pw  = (const float*)d_in[9];
  const float* pb  = (const float*)d_in[10];
  float* out = (float*)d_out;

  float* ws     = (float*)d_ws;
  float* stats  = ws;                              // 2 f32
  u32*   bounds = (u32*)(ws + 4);                  // 4 u32
  u16* wqb = (u16*)(ws + 64);                      // 4 x 16384 bf16 = 128 KB
  u16* wkb = wqb + 16384;
  u16* wvb = wkb + 16384;
  u16* wpb = wvb + 16384;
  u16* qbuf = wpb + 16384;                         // [h][n][d] 1 MB
  u16* kbuf = qbuf + NTOT;                         // [h][n][d] 1 MB
  u16* vbuf = kbuf + NTOT;                         // [h][d][n] 1 MB
  float* Opart = (float*)(vbuf + NTOT);            // [2][h][q][d] f32 = 4 MB
  float* lpart = Opart + 2 * (size_t)NTOT;         // [2][h][q] f32 = 128 KB

  hipMemsetAsync(d_ws, 0, 256, stream);            // stats + bounds

  gn_prep_k<<<256, 256, 0, stream>>>(x, stats, qw, kw, vw, pw, wqb, wkb, wvb, wpb);
  qkv_k<<<256, 256, 0, stream>>>(x, gnw, gnb, stats, wqb, wkb, wvb,
                                 qb, kb, vb, qbuf, kbuf, vbuf, bounds);
  attn_k<<<512, 256, 0, stream>>>(qbuf, kbuf, vbuf, bounds, Opart, lpart);
  proj_k<<<256, 256, 0, stream>>>(Opart, lpart, wpb, pb, x, out);
}

// Round 4
// 145.585 us; speedup vs baseline: 1.7784x; 1.1844x over previous
//
#include <hip/hip_runtime.h>

#define NPOS 4096
#define NCH  128
#define NTOT (NPOS * NCH)   // 524288
#define NHEAD 4
#define DH    32
#define NSPLIT 4
#define KSPAN (NPOS / NSPLIT)   // 1024 keys per split

typedef __attribute__((ext_vector_type(8))) short short8;   // 8 bf16
typedef __attribute__((ext_vector_type(4))) float floatx4;  // MFMA acc
typedef unsigned short u16;
typedef unsigned int   u32;

__device__ __forceinline__ u16 f2bf(float f) {              // RNE
  u32 u = __float_as_uint(f);
  u += 0x7fffu + ((u >> 16) & 1u);
  return (u16)(u >> 16);
}
__device__ __forceinline__ u32 pack2bf(float a, float b) {
  return (u32)f2bf(a) | ((u32)f2bf(b) << 16);
}
__device__ __forceinline__ u32 pack2bf_fast(float a, float b) {  // round-half-up
  return ((__float_as_uint(a) + 0x8000u) >> 16) |
         ((__float_as_uint(b) + 0x8000u) & 0xffff0000u);
}
__device__ __forceinline__ float bf2f(u16 h) {
  return __uint_as_float(((u32)h) << 16);
}

// ---------------- GN partial sums (atomic-free) + weight bf16 prep ----------------
__global__ __launch_bounds__(256) void gn_prep_k(const float* __restrict__ x,
                                                 float2* __restrict__ partials,
                                                 u32* __restrict__ bounds,
                                                 const float* __restrict__ qw, const float* __restrict__ kw,
                                                 const float* __restrict__ vw, const float* __restrict__ pw,
                                                 u16* __restrict__ wq, u16* __restrict__ wk,
                                                 u16* __restrict__ wv, u16* __restrict__ wp) {
  int i = blockIdx.x * 256 + threadIdx.x;           // 0..65535
  int w = threadIdx.x >> 6, lane = threadIdx.x & 63;
  float4 a = ((const float4*)x)[i];
  float4 b = ((const float4*)x)[i + 65536];
  float s  = a.x + a.y + a.z + a.w + b.x + b.y + b.z + b.w;
  float sq = a.x*a.x + a.y*a.y + a.z*a.z + a.w*a.w
           + b.x*b.x + b.y*b.y + b.z*b.z + b.w*b.w;
#pragma unroll
  for (int m = 1; m < 64; m <<= 1) {
    s  += __shfl_xor(s, m);
    sq += __shfl_xor(sq, m);
  }
  __shared__ float red[8];
  if (lane == 0) { red[w] = s; red[4 + w] = sq; }
  __syncthreads();
  if (threadIdx.x == 0)
    partials[blockIdx.x] = make_float2(red[0]+red[1]+red[2]+red[3],
                                       red[4]+red[5]+red[6]+red[7]);
  if (blockIdx.x == 0 && threadIdx.x < 4) bounds[threadIdx.x] = 0;
  if (blockIdx.x < 16) {
    int t = blockIdx.x * 256 + threadIdx.x;         // 0..4095 float4 idx into 128x128
    const float sc = 0.17677669529663687f * 1.4426950408889634f;  // d^-0.5 * log2e
    float4 v = ((const float4*)qw)[t];
    ((uint2*)wq)[t] = make_uint2(pack2bf(v.x*sc, v.y*sc), pack2bf(v.z*sc, v.w*sc));
    v = ((const float4*)kw)[t];
    ((uint2*)wk)[t] = make_uint2(pack2bf(v.x, v.y), pack2bf(v.z, v.w));
    v = ((const float4*)vw)[t];
    ((uint2*)wv)[t] = make_uint2(pack2bf(v.x, v.y), pack2bf(v.z, v.w));
    v = ((const float4*)pw)[t];
    ((uint2*)wp)[t] = make_uint2(pack2bf(v.x, v.y), pack2bf(v.z, v.w));
  }
}

// ---------------- fused GN-normalize + QKV GEMM (MFMA), LDS-staged h ----------------
// grid 256; wave w = head w; n-tile 16. q,k out [h][n][d]; v out [h][d][n].
__global__ __launch_bounds__(256) void qkv_k(const float* __restrict__ x,
    const float* __restrict__ gw, const float* __restrict__ gb,
    const float2* __restrict__ partials,
    const u16* __restrict__ wq, const u16* __restrict__ wk, const u16* __restrict__ wv,
    const float* __restrict__ qb, const float* __restrict__ kb, const float* __restrict__ vb,
    u16* __restrict__ q, u16* __restrict__ k, u16* __restrict__ v, u32* __restrict__ bounds) {
  const int t = threadIdx.x;
  const int w = t >> 6, lane = t & 63;
  const int l16 = lane & 15, quad = lane >> 4;
  const int n0 = blockIdx.x * 16, ow = w * 32;
  const floatx4 zero = {0.f, 0.f, 0.f, 0.f};

  __shared__ float red[8];
  __shared__ float2 swb[128];
  __shared__ __align__(16) u16 hs[16][136];        // [n-local][c], +8 pad

  // per-block stats reduce (2KB of partials, L2-hot)
  float2 p = partials[t];
  float s = p.x, sq = p.y;
#pragma unroll
  for (int m = 1; m < 64; m <<= 1) {
    s  += __shfl_xor(s, m);
    sq += __shfl_xor(sq, m);
  }
  if (lane == 0) { red[w] = s; red[4 + w] = sq; }
  __syncthreads();
  float mean = (red[0]+red[1]+red[2]+red[3]) * (1.0f / NTOT);
  float var  = (red[4]+red[5]+red[6]+red[7]) * (1.0f / NTOT) - mean * mean;
  float rstd = rsqrtf(var + 1e-5f);
  if (t < 128) {
    float swv = gw[t] * rstd;
    swb[t] = make_float2(swv, gb[t] - mean * swv);
  }
  __syncthreads();

  // stage GN'd h tile as bf16 [n][c]
#pragma unroll
  for (int i = t; i < 512; i += 256) {
    int c = i >> 2, seg = i & 3;
    float4 xv = *(const float4*)(x + (size_t)c * NPOS + n0 + seg * 4);
    float2 sb = swb[c];
    int nl = seg * 4;
    hs[nl + 0][c] = f2bf(xv.x * sb.x + sb.y);
    hs[nl + 1][c] = f2bf(xv.y * sb.x + sb.y);
    hs[nl + 2][c] = f2bf(xv.z * sb.x + sb.y);
    hs[nl + 3][c] = f2bf(xv.w * sb.x + sb.y);
  }
  __syncthreads();

  short8 bfr[4];
#pragma unroll
  for (int kk = 0; kk < 4; kk++)
    bfr[kk] = *(const short8*)&hs[l16][kk * 32 + quad * 8];

  const int n = n0 + l16;
  // ---- Q
  {
    floatx4 a0 = zero, a1 = zero;
    const u16* ap = wq + (size_t)(ow + l16) * NCH + quad * 8;
#pragma unroll
    for (int kk = 0; kk < 4; kk++) {
      a0 = __builtin_amdgcn_mfma_f32_16x16x32_bf16(*(const short8*)(ap + kk*32),          bfr[kk], a0, 0,0,0);
      a1 = __builtin_amdgcn_mfma_f32_16x16x32_bf16(*(const short8*)(ap + 16*NCH + kk*32), bfr[kk], a1, 0,0,0);
    }
    const float sc = 0.17677669529663687f * 1.4426950408889634f;
    u16* qp = q + (size_t)(w * NPOS + n) * DH;
#pragma unroll
    for (int ss = 0; ss < 2; ss++) {
      floatx4 acc = ss ? a1 : a0;
      int od = ss * 16 + quad * 4;
      float r0 = acc[0] + qb[ow+od+0]*sc, r1 = acc[1] + qb[ow+od+1]*sc;
      float r2 = acc[2] + qb[ow+od+2]*sc, r3 = acc[3] + qb[ow+od+3]*sc;
      *(uint2*)(qp + od) = make_uint2(pack2bf(r0, r1), pack2bf(r2, r3));
    }
  }
  // ---- K (+ per-head max ||k||^2)
  {
    floatx4 a0 = zero, a1 = zero;
    const u16* ap = wk + (size_t)(ow + l16) * NCH + quad * 8;
#pragma unroll
    for (int kk = 0; kk < 4; kk++) {
      a0 = __builtin_amdgcn_mfma_f32_16x16x32_bf16(*(const short8*)(ap + kk*32),          bfr[kk], a0, 0,0,0);
      a1 = __builtin_amdgcn_mfma_f32_16x16x32_bf16(*(const short8*)(ap + 16*NCH + kk*32), bfr[kk], a1, 0,0,0);
    }
    float sumsq = 0.f;
    u16* kp = k + (size_t)(w * NPOS + n) * DH;
#pragma unroll
    for (int ss = 0; ss < 2; ss++) {
      floatx4 acc = ss ? a1 : a0;
      int od = ss * 16 + quad * 4;
      float r0 = acc[0] + kb[ow+od+0], r1 = acc[1] + kb[ow+od+1];
      float r2 = acc[2] + kb[ow+od+2], r3 = acc[3] + kb[ow+od+3];
      sumsq += r0*r0 + r1*r1 + r2*r2 + r3*r3;
      *(uint2*)(kp + od) = make_uint2(pack2bf(r0, r1), pack2bf(r2, r3));
    }
    sumsq += __shfl_xor(sumsq, 16);
    sumsq += __shfl_xor(sumsq, 32);
#pragma unroll
    for (int m = 1; m < 16; m <<= 1) sumsq = fmaxf(sumsq, __shfl_xor(sumsq, m));
    if (lane == 0) atomicMax(&bounds[w], __float_as_uint(sumsq));
  }
  // ---- V
  {
    floatx4 a0 = zero, a1 = zero;
    const u16* ap = wv + (size_t)(ow + l16) * NCH + quad * 8;
#pragma unroll
    for (int kk = 0; kk < 4; kk++) {
      a0 = __builtin_amdgcn_mfma_f32_16x16x32_bf16(*(const short8*)(ap + kk*32),          bfr[kk], a0, 0,0,0);
      a1 = __builtin_amdgcn_mfma_f32_16x16x32_bf16(*(const short8*)(ap + 16*NCH + kk*32), bfr[kk], a1, 0,0,0);
    }
    u16* vp = v + (size_t)(w * DH) * NPOS + n;
#pragma unroll
    for (int ss = 0; ss < 2; ss++) {
      floatx4 acc = ss ? a1 : a0;
      int od = ss * 16 + quad * 4;
#pragma unroll
      for (int r = 0; r < 4; r++)
        vp[(size_t)(od + r) * NPOS] = f2bf(acc[r] + vb[ow + od + r]);
    }
  }
}

// ---------------- flash attention, S^T form, 4-way split-K ----------------
// grid 1024 x 256: block b -> (split s = b>>8, qtile = b&255); wave w = head.
// Opair[s][h][q][d16] u32: packed (d, d+16) bf16 pair; lpart[s][h][q] f32.
__global__ __launch_bounds__(256) void attn_k(const u16* __restrict__ q, const u16* __restrict__ k,
                                              const u16* __restrict__ v, const u32* __restrict__ bounds,
                                              u32* __restrict__ Opair, float* __restrict__ lpart) {
  const int w = threadIdx.x >> 6, lane = threadIdx.x & 63;
  const int l16 = lane & 15, quad = lane >> 4;
  const int s = blockIdx.x >> 8;
  const int q0 = (blockIdx.x & 255) * 16;
  const int head = w;
  __shared__ __align__(16) u16 p_lds[4][2][16][72];   // per-wave double-buffered P

  short8 bq = *(const short8*)(q + (size_t)(head * NPOS + q0 + l16) * DH + quad * 8);
  float qn2 = 0.f;
#pragma unroll
  for (int j = 0; j < 8; j++) { float f = bf2f((u16)bq[j]); qn2 += f * f; }
  qn2 += __shfl_xor(qn2, 16);
  qn2 += __shfl_xor(qn2, 32);
  float kmax = sqrtf(__uint_as_float(bounds[head])) * 1.0005f;
  float bound = sqrtf(qn2) * kmax;

  floatx4 o0 = {0,0,0,0}, o1 = {0,0,0,0}, ol = {0,0,0,0};
  short8 ones;
#pragma unroll
  for (int j = 0; j < 8; j++) ones[j] = (short)0x3F80;   // bf16 1.0

  const u16* kbp = k + (size_t)head * NPOS * DH;
  const u16* vb0 = v + (size_t)(head * DH + l16) * NPOS;
  const u16* vb1 = v + (size_t)(head * DH + 16 + l16) * NPOS;
  const floatx4 zero = {0,0,0,0};
  const int m0beg = s * KSPAN;

#pragma unroll 2
  for (int it = 0; it < KSPAN / 64; it++) {
    const int m0 = m0beg + it * 64;
    const int buf = it & 1;
    floatx4 c[4];
#pragma unroll
    for (int sub = 0; sub < 4; sub++) {
      short8 ak = *(const short8*)(kbp + (size_t)(m0 + sub*16 + l16) * DH + quad * 8);
      c[sub] = __builtin_amdgcn_mfma_f32_16x16x32_bf16(ak, bq, zero, 0, 0, 0);
    }
#pragma unroll
    for (int sub = 0; sub < 4; sub++) {
      float p0 = __builtin_amdgcn_exp2f(c[sub][0] - bound);
      float p1 = __builtin_amdgcn_exp2f(c[sub][1] - bound);
      float p2 = __builtin_amdgcn_exp2f(c[sub][2] - bound);
      float p3 = __builtin_amdgcn_exp2f(c[sub][3] - bound);
      *(uint2*)&p_lds[w][buf][l16][sub * 16 + quad * 4] =
          make_uint2(pack2bf_fast(p0, p1), pack2bf_fast(p2, p3));
    }
#pragma unroll
    for (int kc = 0; kc < 2; kc++) {
      short8 pa  = *(const short8*)&p_lds[w][buf][l16][kc * 32 + quad * 8];
      short8 av0 = *(const short8*)(vb0 + m0 + kc * 32 + quad * 8);
      short8 av1 = *(const short8*)(vb1 + m0 + kc * 32 + quad * 8);
      o0 = __builtin_amdgcn_mfma_f32_16x16x32_bf16(pa, av0, o0, 0, 0, 0);
      o1 = __builtin_amdgcn_mfma_f32_16x16x32_bf16(pa, av1, o1, 0, 0, 0);
      ol = __builtin_amdgcn_mfma_f32_16x16x32_bf16(pa, ones, ol, 0, 0, 0);
    }
  }

  u32*   op = Opair + (size_t)(s * NHEAD + head) * NPOS * 16;
  float* lp = lpart + (size_t)(s * NHEAD + head) * NPOS;
#pragma unroll
  for (int r = 0; r < 4; r++) {
    int qq = q0 + quad * 4 + r;
    op[(size_t)qq * 16 + l16] = pack2bf(o0[r], o1[r]);
    if (l16 == 0) lp[qq] = ol[r];
  }
}

// ---------------- proj GEMM: inline 4-way split-combine + bias + residual ----------------
__global__ __launch_bounds__(256) void proj_k(const u32* __restrict__ Opair,
                                              const float* __restrict__ lpart,
                                              const u16* __restrict__ wp,
                                              const float* __restrict__ pb,
                                              const float* __restrict__ x,
                                              float* __restrict__ out) {
  const int w = threadIdx.x >> 6, lane = threadIdx.x & 63;
  const int l16 = lane & 15, quad = lane >> 4;
  const int n0 = blockIdx.x * 16, ow = w * 32;
  const int n = n0 + l16;
  const floatx4 zero = {0.f, 0.f, 0.f, 0.f};
  const bool hi = quad >= 2;

  short8 bfr[4];
#pragma unroll
  for (int kk = 0; kk < 4; kk++) {
    float acc8[8] = {0,0,0,0,0,0,0,0};
    float l = 0.f;
#pragma unroll
    for (int s2 = 0; s2 < NSPLIT; s2++) {
      const u32* pp = Opair + ((size_t)(s2 * NHEAD + kk) * NPOS + n) * 16 + (quad & 1) * 8;
      uint4 u0 = *(const uint4*)pp;
      uint4 u1 = *(const uint4*)(pp + 4);
      u32 uu[8] = {u0.x, u0.y, u0.z, u0.w, u1.x, u1.y, u1.z, u1.w};
#pragma unroll
      for (int j = 0; j < 8; j++)
        acc8[j] += __uint_as_float(hi ? (uu[j] & 0xffff0000u) : (uu[j] << 16));
      l += lpart[(size_t)(s2 * NHEAD + kk) * NPOS + n];
    }
    float inv = 1.0f / fmaxf(l, 1e-30f);
    uint4 u = make_uint4(pack2bf(acc8[0]*inv, acc8[1]*inv),
                         pack2bf(acc8[2]*inv, acc8[3]*inv),
                         pack2bf(acc8[4]*inv, acc8[5]*inv),
                         pack2bf(acc8[6]*inv, acc8[7]*inv));
    bfr[kk] = *(short8*)&u;
  }
  floatx4 a0 = zero, a1 = zero;
  const u16* ap = wp + (size_t)(ow + l16) * NCH + quad * 8;
#pragma unroll
  for (int kk = 0; kk < 4; kk++) {
    a0 = __builtin_amdgcn_mfma_f32_16x16x32_bf16(*(const short8*)(ap + kk*32),          bfr[kk], a0, 0,0,0);
    a1 = __builtin_amdgcn_mfma_f32_16x16x32_bf16(*(const short8*)(ap + 16*NCH + kk*32), bfr[kk], a1, 0,0,0);
  }
#pragma unroll
  for (int ss = 0; ss < 2; ss++) {
    floatx4 acc = ss ? a1 : a0;
    int o = ow + ss * 16 + quad * 4;
#pragma unroll
    for (int r = 0; r < 4; r++) {
      size_t idx = (size_t)(o + r) * NPOS + n;
      out[idx] = acc[r] + pb[o + r] + x[idx];
    }
  }
}

extern "C" void kernel_launch(void* const* d_in, const int* in_sizes, int n_in,
                              void* d_out, int out_size, void* d_ws, size_t ws_size,
                              hipStream_t stream) {
  const float* x   = (const float*)d_in[0];
  const float* gnw = (const float*)d_in[1];
  const float* gnb = (const float*)d_in[2];
  const float* qw  = (const float*)d_in[3];
  const float* qb  = (const float*)d_in[4];
  const float* kw  = (const float*)d_in[5];
  const float* kb  = (const float*)d_in[6];
  const float* vw  = (const float*)d_in[7];
  const float* vb  = (const float*)d_in[8];
  const float* pw  = (const float*)d_in[9];
  const float* pb  = (const float*)d_in[10];
  float* out = (float*)d_out;

  char* wsb = (char*)d_ws;
  float2* partials = (float2*)wsb;                       // 2 KB
  u32*    bounds   = (u32*)(wsb + 2048);                 // 16 B
  u16* wqb = (u16*)(wsb + 4096);                         // 4 x 32 KB
  u16* wkb = wqb + 16384;
  u16* wvb = wkb + 16384;
  u16* wpb = wvb + 16384;
  u16* qbuf = wpb + 16384;                               // [h][n][d] 1 MB
  u16* kbuf = qbuf + NTOT;                               // [h][n][d] 1 MB
  u16* vbuf = kbuf + NTOT;                               // [h][d][n] 1 MB
  u32* Opair = (u32*)(vbuf + NTOT);                      // [4][h][q][16] u32 = 4 MB
  float* lpart = (float*)(Opair + (size_t)NSPLIT * NHEAD * NPOS * 16);  // 256 KB

  gn_prep_k<<<256, 256, 0, stream>>>(x, partials, bounds, qw, kw, vw, pw,
                                     wqb, wkb, wvb, wpb);
  qkv_k<<<256, 256, 0, stream>>>(x, gnw, gnb, partials, wqb, wkb, wvb,
                                 qb, kb, vb, qbuf, kbuf, vbuf, bounds);
  attn_k<<<1024, 256, 0, stream>>>(qbuf, kbuf, vbuf, bounds, Opair, lpart);
  proj_k<<<256, 256, 0, stream>>>(Opair, lpart, wpb, pb, x, out);
}

// Round 5
// 144.466 us; speedup vs baseline: 1.7922x; 1.0077x over previous
//
#include <hip/hip_runtime.h>

#define NPOS 4096
#define NCH  128
#define NTOT (NPOS * NCH)   // 524288
#define NHEAD 4
#define DH    32
#define NSPLIT 4
#define KSPAN (NPOS / NSPLIT)   // 1024 keys per split
#define NTILE (KSPAN / 64)      // 16 tiles per split

typedef __attribute__((ext_vector_type(8))) short short8;   // 8 bf16
typedef __attribute__((ext_vector_type(4))) float floatx4;  // MFMA acc
typedef unsigned short u16;
typedef unsigned int   u32;

__device__ __forceinline__ u16 f2bf(float f) {              // RNE
  u32 u = __float_as_uint(f);
  u += 0x7fffu + ((u >> 16) & 1u);
  return (u16)(u >> 16);
}
__device__ __forceinline__ u32 pack2bf(float a, float b) {
  return (u32)f2bf(a) | ((u32)f2bf(b) << 16);
}
__device__ __forceinline__ u32 pack2bf_fast(float a, float b) {  // round-half-up
  return ((__float_as_uint(a) + 0x8000u) >> 16) |
         ((__float_as_uint(b) + 0x8000u) & 0xffff0000u);
}
__device__ __forceinline__ float bf2f(u16 h) {
  return __uint_as_float(((u32)h) << 16);
}

// ---------------- GN partial sums (512 blocks) + weight bf16 prep ----------------
__global__ __launch_bounds__(256) void gn_prep_k(const float* __restrict__ x,
                                                 float2* __restrict__ partials,
                                                 u32* __restrict__ bounds,
                                                 const float* __restrict__ qw, const float* __restrict__ kw,
                                                 const float* __restrict__ vw, const float* __restrict__ pw,
                                                 u16* __restrict__ wq, u16* __restrict__ wk,
                                                 u16* __restrict__ wv, u16* __restrict__ wp) {
  int i = blockIdx.x * 256 + threadIdx.x;           // 0..131071 float4
  int w = threadIdx.x >> 6, lane = threadIdx.x & 63;
  float4 a = ((const float4*)x)[i];
  float s  = a.x + a.y + a.z + a.w;
  float sq = a.x*a.x + a.y*a.y + a.z*a.z + a.w*a.w;
#pragma unroll
  for (int m = 1; m < 64; m <<= 1) {
    s  += __shfl_xor(s, m);
    sq += __shfl_xor(sq, m);
  }
  __shared__ float red[8];
  if (lane == 0) { red[w] = s; red[4 + w] = sq; }
  __syncthreads();
  if (threadIdx.x == 0)
    partials[blockIdx.x] = make_float2(red[0]+red[1]+red[2]+red[3],
                                       red[4]+red[5]+red[6]+red[7]);
  if (blockIdx.x == 0 && threadIdx.x < 4) bounds[threadIdx.x] = 0;
  if (blockIdx.x < 16) {
    int t = blockIdx.x * 256 + threadIdx.x;         // 0..4095 float4 idx into 128x128
    const float sc = 0.17677669529663687f * 1.4426950408889634f;  // d^-0.5 * log2e
    float4 v = ((const float4*)qw)[t];
    ((uint2*)wq)[t] = make_uint2(pack2bf(v.x*sc, v.y*sc), pack2bf(v.z*sc, v.w*sc));
    v = ((const float4*)kw)[t];
    ((uint2*)wk)[t] = make_uint2(pack2bf(v.x, v.y), pack2bf(v.z, v.w));
    v = ((const float4*)vw)[t];
    ((uint2*)wv)[t] = make_uint2(pack2bf(v.x, v.y), pack2bf(v.z, v.w));
    v = ((const float4*)pw)[t];
    ((uint2*)wp)[t] = make_uint2(pack2bf(v.x, v.y), pack2bf(v.z, v.w));
  }
}

// ---------------- fused GN + QKV GEMM: 12 waves = 3 mats x 4 heads ----------------
// grid 256 x 768. q,k out [h][n][d]; v out [h][d][n]; bounds[h] = max ||k_n||^2.
__global__ __launch_bounds__(768) void qkv_k(const float* __restrict__ x,
    const float* __restrict__ gw, const float* __restrict__ gb,
    const float2* __restrict__ partials,
    const u16* __restrict__ wq, const u16* __restrict__ wk, const u16* __restrict__ wv,
    const float* __restrict__ qb, const float* __restrict__ kb, const float* __restrict__ vb,
    u16* __restrict__ q, u16* __restrict__ k, u16* __restrict__ v, u32* __restrict__ bounds) {
  const int t = threadIdx.x;
  const int w = t >> 6, lane = t & 63;
  const int l16 = lane & 15, quad = lane >> 4;
  const int n0 = blockIdx.x * 16;
  const floatx4 zero = {0.f, 0.f, 0.f, 0.f};

  __shared__ float red[16];
  __shared__ float2 swb[128];
  __shared__ __align__(16) u16 hs[16][136];        // [n-local][c], padded

  if (t < 512) {
    float2 p = partials[t];
    float s = p.x, sq = p.y;
#pragma unroll
    for (int m = 1; m < 64; m <<= 1) {
      s  += __shfl_xor(s, m);
      sq += __shfl_xor(sq, m);
    }
    if (lane == 0) { red[w] = s; red[8 + w] = sq; }
  }
  __syncthreads();
  float mean = (red[0]+red[1]+red[2]+red[3]+red[4]+red[5]+red[6]+red[7]) * (1.0f / NTOT);
  float var  = (red[8]+red[9]+red[10]+red[11]+red[12]+red[13]+red[14]+red[15]) * (1.0f / NTOT)
               - mean * mean;
  float rstd = rsqrtf(var + 1e-5f);
  if (t < 128) {
    float swv = gw[t] * rstd;
    swb[t] = make_float2(swv, gb[t] - mean * swv);
  }
  __syncthreads();
  if (t < 512) {
    int c = t >> 2, seg = t & 3;
    float4 xv = *(const float4*)(x + (size_t)c * NPOS + n0 + seg * 4);
    float2 sb = swb[c];
    int nl = seg * 4;
    hs[nl + 0][c] = f2bf(xv.x * sb.x + sb.y);
    hs[nl + 1][c] = f2bf(xv.y * sb.x + sb.y);
    hs[nl + 2][c] = f2bf(xv.z * sb.x + sb.y);
    hs[nl + 3][c] = f2bf(xv.w * sb.x + sb.y);
  }
  __syncthreads();

  short8 bfr[4];
#pragma unroll
  for (int kk = 0; kk < 4; kk++)
    bfr[kk] = *(const short8*)&hs[l16][kk * 32 + quad * 8];

  const int mat = w >> 2, head = w & 3, ow = head * 32;
  const u16* wm = (mat == 0) ? wq : (mat == 1) ? wk : wv;
  floatx4 a0 = zero, a1 = zero;
  const u16* ap = wm + (size_t)(ow + l16) * NCH + quad * 8;
#pragma unroll
  for (int kk = 0; kk < 4; kk++) {
    a0 = __builtin_amdgcn_mfma_f32_16x16x32_bf16(*(const short8*)(ap + kk*32),          bfr[kk], a0, 0,0,0);
    a1 = __builtin_amdgcn_mfma_f32_16x16x32_bf16(*(const short8*)(ap + 16*NCH + kk*32), bfr[kk], a1, 0,0,0);
  }
  const int n = n0 + l16;
  if (mat == 0) {
    const float sc = 0.17677669529663687f * 1.4426950408889634f;
    u16* qp = q + (size_t)(head * NPOS + n) * DH;
#pragma unroll
    for (int ss = 0; ss < 2; ss++) {
      floatx4 acc = ss ? a1 : a0;
      int od = ss * 16 + quad * 4;
      float r0 = acc[0] + qb[ow+od+0]*sc, r1 = acc[1] + qb[ow+od+1]*sc;
      float r2 = acc[2] + qb[ow+od+2]*sc, r3 = acc[3] + qb[ow+od+3]*sc;
      *(uint2*)(qp + od) = make_uint2(pack2bf(r0, r1), pack2bf(r2, r3));
    }
  } else if (mat == 1) {
    float sumsq = 0.f;
    u16* kp = k + (size_t)(head * NPOS + n) * DH;
#pragma unroll
    for (int ss = 0; ss < 2; ss++) {
      floatx4 acc = ss ? a1 : a0;
      int od = ss * 16 + quad * 4;
      float r0 = acc[0] + kb[ow+od+0], r1 = acc[1] + kb[ow+od+1];
      float r2 = acc[2] + kb[ow+od+2], r3 = acc[3] + kb[ow+od+3];
      sumsq += r0*r0 + r1*r1 + r2*r2 + r3*r3;
      *(uint2*)(kp + od) = make_uint2(pack2bf(r0, r1), pack2bf(r2, r3));
    }
    sumsq += __shfl_xor(sumsq, 16);
    sumsq += __shfl_xor(sumsq, 32);
#pragma unroll
    for (int m = 1; m < 16; m <<= 1) sumsq = fmaxf(sumsq, __shfl_xor(sumsq, m));
    if (lane == 0) atomicMax(&bounds[head], __float_as_uint(sumsq));
  } else {
    u16* vp = v + (size_t)(head * DH) * NPOS + n;
#pragma unroll
    for (int ss = 0; ss < 2; ss++) {
      floatx4 acc = ss ? a1 : a0;
      int od = ss * 16 + quad * 4;
#pragma unroll
      for (int r = 0; r < 4; r++)
        vp[(size_t)(od + r) * NPOS] = f2bf(acc[r] + vb[ow + od + r]);
    }
  }
}

// ---------------- flash attention: software-pipelined global prefetch ----------------
// grid 1024 x 256: block b -> (split s = b>>8, qtile = b&255); wave w = head.
__global__ __launch_bounds__(256) void attn_k(const u16* __restrict__ q, const u16* __restrict__ k,
                                              const u16* __restrict__ v, const u32* __restrict__ bounds,
                                              u32* __restrict__ Opair, float* __restrict__ lpart) {
  const int w = threadIdx.x >> 6, lane = threadIdx.x & 63;
  const int l16 = lane & 15, quad = lane >> 4;
  const int s = blockIdx.x >> 8;
  const int q0 = (blockIdx.x & 255) * 16;
  const int head = w;
  __shared__ __align__(16) u16 p_lds[4][2][16][72];   // per-wave double-buffered P

  short8 bq = *(const short8*)(q + (size_t)(head * NPOS + q0 + l16) * DH + quad * 8);
  float qn2 = 0.f;
#pragma unroll
  for (int j = 0; j < 8; j++) { float f = bf2f((u16)bq[j]); qn2 += f * f; }
  qn2 += __shfl_xor(qn2, 16);
  qn2 += __shfl_xor(qn2, 32);
  float kmax = sqrtf(__uint_as_float(bounds[head])) * 1.0005f;
  float bound = sqrtf(qn2) * kmax;

  floatx4 o0 = {0,0,0,0}, o1 = {0,0,0,0}, ol = {0,0,0,0};
  short8 ones;
#pragma unroll
  for (int j = 0; j < 8; j++) ones[j] = (short)0x3F80;   // bf16 1.0

  const u16* kbp = k + (size_t)head * NPOS * DH + quad * 8;
  const u16* vb0 = v + (size_t)(head * DH + l16) * NPOS + quad * 8;
  const u16* vb1 = vb0 + (size_t)16 * NPOS;
  const floatx4 zero = {0,0,0,0};

  int m0 = s * KSPAN;
  short8 ak[4], av[4];
#pragma unroll
  for (int sub = 0; sub < 4; sub++)
    ak[sub] = *(const short8*)(kbp + (size_t)(m0 + sub * 16 + l16) * DH);
#pragma unroll
  for (int kc = 0; kc < 2; kc++) {
    av[2*kc]   = *(const short8*)(vb0 + m0 + kc * 32);
    av[2*kc+1] = *(const short8*)(vb1 + m0 + kc * 32);
  }

  for (int it = 0; it < NTILE; it++) {
    const int mn = m0 + 64;
    const bool more = (it + 1 < NTILE);
    short8 nak[4], nav[4];
    if (more) {                                      // prefetch tile it+1 into regs
#pragma unroll
      for (int sub = 0; sub < 4; sub++)
        nak[sub] = *(const short8*)(kbp + (size_t)(mn + sub * 16 + l16) * DH);
#pragma unroll
      for (int kc = 0; kc < 2; kc++) {
        nav[2*kc]   = *(const short8*)(vb0 + mn + kc * 32);
        nav[2*kc+1] = *(const short8*)(vb1 + mn + kc * 32);
      }
    }
    const int buf = it & 1;
    floatx4 c[4];
#pragma unroll
    for (int sub = 0; sub < 4; sub++)
      c[sub] = __builtin_amdgcn_mfma_f32_16x16x32_bf16(ak[sub], bq, zero, 0, 0, 0);
#pragma unroll
    for (int sub = 0; sub < 4; sub++) {
      float p0 = __builtin_amdgcn_exp2f(c[sub][0] - bound);
      float p1 = __builtin_amdgcn_exp2f(c[sub][1] - bound);
      float p2 = __builtin_amdgcn_exp2f(c[sub][2] - bound);
      float p3 = __builtin_amdgcn_exp2f(c[sub][3] - bound);
      *(uint2*)&p_lds[w][buf][l16][sub * 16 + quad * 4] =
          make_uint2(pack2bf_fast(p0, p1), pack2bf_fast(p2, p3));
    }
#pragma unroll
    for (int kc = 0; kc < 2; kc++) {
      short8 pa = *(const short8*)&p_lds[w][buf][l16][kc * 32 + quad * 8];
      o0 = __builtin_amdgcn_mfma_f32_16x16x32_bf16(pa, av[2*kc],   o0, 0, 0, 0);
      o1 = __builtin_amdgcn_mfma_f32_16x16x32_bf16(pa, av[2*kc+1], o1, 0, 0, 0);
      ol = __builtin_amdgcn_mfma_f32_16x16x32_bf16(pa, ones,       ol, 0, 0, 0);
    }
    if (more) {
#pragma unroll
      for (int j = 0; j < 4; j++) { ak[j] = nak[j]; av[j] = nav[j]; }
    }
    m0 = mn;
  }

  u32*   op = Opair + (size_t)(s * NHEAD + head) * NPOS * 16;
  float* lp = lpart + (size_t)(s * NHEAD + head) * NPOS;
#pragma unroll
  for (int r = 0; r < 4; r++) {
    int qq = q0 + quad * 4 + r;
    op[(size_t)qq * 16 + l16] = pack2bf(o0[r], o1[r]);
    if (l16 == 0) lp[qq] = ol[r];
  }
}

// ---------------- proj GEMM: LDS-deduped split combine, 8 waves ----------------
// grid 256 x 512; wave w: out rows w*16..w*16+15.
__global__ __launch_bounds__(512) void proj_k(const u32* __restrict__ Opair,
                                              const float* __restrict__ lpart,
                                              const u16* __restrict__ wp,
                                              const float* __restrict__ pb,
                                              const float* __restrict__ x,
                                              float* __restrict__ out) {
  const int t = threadIdx.x;
  const int w = t >> 6, lane = t & 63;
  const int l16 = lane & 15, quad = lane >> 4;
  const int n0 = blockIdx.x * 16;
  const floatx4 zero = {0.f, 0.f, 0.f, 0.f};
  __shared__ __align__(16) u16 at_lds[16][136];

  {                                                  // cooperative combine: 512 thr x 4 ch
    const int n = t & 15, ci = t >> 4;               // ci 0..31
    const int c0 = ci * 4, head = c0 >> 5, off = c0 & 31;
    const int half = off >> 4, j0 = off & 15;
    float acc[4] = {0.f, 0.f, 0.f, 0.f};
    float l = 0.f;
#pragma unroll
    for (int s2 = 0; s2 < NSPLIT; s2++) {
      const u32* pp = Opair + ((size_t)(s2 * NHEAD + head) * NPOS + n0 + n) * 16 + j0;
      uint4 u = *(const uint4*)pp;
      u32 uu[4] = {u.x, u.y, u.z, u.w};
#pragma unroll
      for (int j = 0; j < 4; j++)
        acc[j] += half ? __uint_as_float(uu[j] & 0xffff0000u)
                       : __uint_as_float(uu[j] << 16);
      l += lpart[(size_t)(s2 * NHEAD + head) * NPOS + n0 + n];
    }
    float inv = 1.0f / fmaxf(l, 1e-30f);
    *(uint2*)&at_lds[n][c0] = make_uint2(pack2bf(acc[0]*inv, acc[1]*inv),
                                         pack2bf(acc[2]*inv, acc[3]*inv));
  }
  __syncthreads();

  short8 bfr[4];
#pragma unroll
  for (int kk = 0; kk < 4; kk++)
    bfr[kk] = *(const short8*)&at_lds[l16][kk * 32 + quad * 8];
  const int ow = w * 16;
  floatx4 a0 = zero;
  const u16* ap = wp + (size_t)(ow + l16) * NCH + quad * 8;
#pragma unroll
  for (int kk = 0; kk < 4; kk++)
    a0 = __builtin_amdgcn_mfma_f32_16x16x32_bf16(*(const short8*)(ap + kk*32), bfr[kk], a0, 0,0,0);
  const int n = n0 + l16;
#pragma unroll
  for (int r = 0; r < 4; r++) {
    int o = ow + quad * 4 + r;
    size_t idx = (size_t)o * NPOS + n;
    out[idx] = a0[r] + pb[o] + x[idx];
  }
}

extern "C" void kernel_launch(void* const* d_in, const int* in_sizes, int n_in,
                              void* d_out, int out_size, void* d_ws, size_t ws_size,
                              hipStream_t stream) {
  const float* x   = (const float*)d_in[0];
  const float* gnw = (const float*)d_in[1];
  const float* gnb = (const float*)d_in[2];
  const float* qw  = (const float*)d_in[3];
  const float* qb  = (const float*)d_in[4];
  const float* kw  = (const float*)d_in[5];
  const float* kb  = (const float*)d_in[6];
  const float* vw  = (const float*)d_in[7];
  const float* vb  = (const float*)d_in[8];
  const float* pw  = (const float*)d_in[9];
  const float* pb  = (const float*)d_in[10];
  float* out = (float*)d_out;

  char* wsb = (char*)d_ws;
  float2* partials = (float2*)wsb;                       // 512 x 8 B = 4 KB
  u32*    bounds   = (u32*)(wsb + 4096);                 // 16 B
  u16* wqb = (u16*)(wsb + 8192);                         // 4 x 32 KB
  u16* wkb = wqb + 16384;
  u16* wvb = wkb + 16384;
  u16* wpb = wvb + 16384;
  u16* qbuf = wpb + 16384;                               // [h][n][d] 1 MB
  u16* kbuf = qbuf + NTOT;                               // [h][n][d] 1 MB
  u16* vbuf = kbuf + NTOT;                               // [h][d][n] 1 MB
  u32* Opair = (u32*)(vbuf + NTOT);                      // [4][h][q][16] u32 = 4 MB
  float* lpart = (float*)(Opair + (size_t)NSPLIT * NHEAD * NPOS * 16);  // 256 KB

  gn_prep_k<<<512, 256, 0, stream>>>(x, partials, bounds, qw, kw, vw, pw,
                                     wqb, wkb, wvb, wpb);
  qkv_k<<<256, 768, 0, stream>>>(x, gnw, gnb, partials, wqb, wkb, wvb,
                                 qb, kb, vb, qbuf, kbuf, vbuf, bounds);
  attn_k<<<256 * NSPLIT, 256, 0, stream>>>(qbuf, kbuf, vbuf, bounds, Opair, lpart);
  proj_k<<<256, 512, 0, stream>>>(Opair, lpart, wpb, pb, x, out);
}